// Round 17
// baseline (142.469 us; speedup 1.0000x reference)
//
#include <hip/hip_runtime.h>

#define NR   8192
#define CIN  200
#define CNN  128
#define BN_EPS 1e-5f

// ws float offsets
#define OFF_BNPART 0                           // 64 blocks * 400
#define OFF_DTH    (OFF_BNPART + 64 * 400)
#define OFF_V2     (OFF_DTH + NR * CNN)        // [NR][8] f32 (cols 0..4 used)
#define OFF_MP     (OFF_V2 + NR * 8)           // 256 * 56 moment partials (iter 1)
#define OFF_WT     (OFF_MP + 256 * 56)         // wdtdT [128][128]
#define OFF_ATM    (OFF_WT + 128 * 128)        // 112 atomic moments + counter

// moment tables: t<5 -> S1[A]; 5<=t<20 -> M2[A][B]; 20<=t<55 -> T3[A][B][C]
__device__ const int MA[55] = {0,1,2,3,4,
    0,0,0,0,0,1,1,1,1,2,2,2,3,3,4,
    0,0,0,0,0,0,0,0,0,0,0,0,0,0,0,
    1,1,1,1,1,1,1,1,1,1,
    2,2,2,2,2,2,
    3,3,3,
    4};
__device__ const int MB[55] = {-1,-1,-1,-1,-1,
    0,1,2,3,4,1,2,3,4,2,3,4,3,4,4,
    0,0,0,0,0,1,1,1,1,2,2,2,3,3,4,
    1,1,1,1,2,2,2,3,3,4,
    2,2,2,3,3,4,
    3,3,4,
    4};
__device__ const int MC[55] = {-1,-1,-1,-1,-1,
    -1,-1,-1,-1,-1,-1,-1,-1,-1,-1,-1,-1,-1,-1,-1,
    0,1,2,3,4,1,2,3,4,2,3,4,3,4,4,
    1,2,3,4,2,3,4,3,4,4,
    2,3,4,3,4,4,
    3,4,4,
    4};

// ---- BN partials (0..63) + wdtd^T (64..79) + atomic-buffer zeroing --------
__global__ __launch_bounds__(256) void bn1_k(
    const float* __restrict__ H, const float* __restrict__ wdtd,
    float* __restrict__ ws)
{
    const int t = threadIdx.x, b = blockIdx.x;
    if (b < 64) {
        if (t >= CIN) return;
        const float* p = H + (size_t)b * 128 * CIN + t;
        float s = 0.f, q = 0.f;
        #pragma unroll 8
        for (int r = 0; r < 128; ++r) { float v = p[(size_t)r * CIN]; s += v; q += v * v; }
        ws[OFF_BNPART + b * 400 + t]       = s;
        ws[OFF_BNPART + b * 400 + 200 + t] = q;
    } else {
        const int n0 = (b - 64) * 8;
        float* wT = ws + OFF_WT;
        #pragma unroll
        for (int i = 0; i < 4; ++i) {
            const int idx = t + i * 256;
            const int dn = idx >> 7, k = idx & 127;
            wT[k * 128 + n0 + dn] = wdtd[(size_t)(n0 + dn) * 128 + k];
        }
        if (b == 64 && t < 120) ws[OFF_ATM + t] = 0.f;   // moments + counter
    }
}

// ---- BN finalize + dual GEMM + l12 epilogue + moment partials (r12) -------
__global__ __launch_bounds__(256) void gemm_bn_k(
    const float* __restrict__ H, const float* __restrict__ w1,
    const float* __restrict__ b1, const float* __restrict__ wdt,
    const float* __restrict__ bdt,
    const float* __restrict__ aw1, const float* __restrict__ ab1,
    const float* __restrict__ aw2, const float* __restrict__ ab2,
    const float* __restrict__ gamma, const float* __restrict__ beta,
    float* __restrict__ ws, float* __restrict__ DTH,
    float* __restrict__ V2g, float* __restrict__ mpart)
{
    __shared__ float smem[8192];
    float* scs  = smem;
    float* shs  = smem + 256;
    float* bias = smem + 512;
    float* aw1s = smem + 768;
    float* aw2s = smem + 2048;
    float* ab1s = smem + 2112;
    float* ab2s = smem + 2128;
    float* As   = smem + 2144;
    float* Bs   = smem + 2432;
    float* Ct   = smem + 3520;
    float* v1s  = smem + 7776;
    float* v2row = smem + 2144;     // reuses As region post-GEMM

    const int t   = threadIdx.x;
    const int bid = blockIdx.x;
    const bool isV = (bid < 256);
    const int  m0  = (bid & 255) * 32;
    const float* bnpart = ws + OFF_BNPART;

    if (t < CIN) {
        float s = 0.f, q = 0.f;
        const float* p = bnpart + t;
        #pragma unroll 8
        for (int b = 0; b < 64; ++b) { s += p[b * 400]; q += p[b * 400 + 200]; }
        float mu  = s * (1.f / NR);
        float var = q * (1.f / NR) - mu * mu;
        float sc  = rsqrtf(var + BN_EPS) * gamma[t];
        scs[t] = sc; shs[t] = beta[t] - mu * sc;
    }
    if (t < CNN) bias[t] = isV ? b1[t] : bdt[t];
    if (isV) {
        for (int i = t; i < 1280; i += 256) aw1s[i] = aw1[i];
        if (t < 50) aw2s[t] = aw2[t];
        if (t < 10) ab1s[t] = ab1[t];
        if (t < 5)  ab2s[t] = ab2[t];
    }
    const int am = t >> 3, ak = t & 7;
    const int bn_ = t >> 1, bk4 = (t & 1) * 4;
    const float* brow = (isV ? w1 : wdt) + (size_t)bn_ * CIN + bk4;
    const float* arow = H + (size_t)(m0 + am) * CIN + ak;
    const int tx = t & 31, ty = t >> 5;
    float acc[4][4] = {};
    __syncthreads();

    for (int k0 = 0; k0 < CIN; k0 += 8) {
        const int k = k0 + ak;
        float  aval = arow[k0] * scs[k] + shs[k];
        float4 bv   = *(const float4*)(brow + k0);
        __syncthreads();
        As[ak * 36 + am] = aval;
        Bs[(bk4 + 0) * 136 + bn_] = bv.x; Bs[(bk4 + 1) * 136 + bn_] = bv.y;
        Bs[(bk4 + 2) * 136 + bn_] = bv.z; Bs[(bk4 + 3) * 136 + bn_] = bv.w;
        __syncthreads();
        #pragma unroll
        for (int kk = 0; kk < 8; ++kk) {
            float4 av  = *(const float4*)&As[kk * 36 + ty * 4];
            float4 bv4 = *(const float4*)&Bs[kk * 136 + tx * 4];
            float a[4] = {av.x, av.y, av.z, av.w};
            float b[4] = {bv4.x, bv4.y, bv4.z, bv4.w};
            #pragma unroll
            for (int i = 0; i < 4; ++i)
                #pragma unroll
                for (int j = 0; j < 4; ++j)
                    acc[i][j] += a[i] * b[j];
        }
    }

    if (isV) {
        #pragma unroll
        for (int i = 0; i < 4; ++i) {
            const int m = ty * 4 + i;
            #pragma unroll
            for (int j = 0; j < 4; ++j) {
                const int n = tx * 4 + j;
                Ct[m * 133 + n] = fmaxf(acc[i][j] + bias[n], 0.f);
            }
        }
        __syncthreads();
        for (int o = ty; o < 10; o += 8) {
            const int row = tx;
            float s = ab1s[o];
            const float* wr = &aw1s[o * 128];
            #pragma unroll 8
            for (int k = 0; k < 128; ++k) s += Ct[row * 133 + k] * wr[k];
            v1s[row * 12 + o] = fmaxf(s, 0.f);
        }
        __syncthreads();
        if (t < 32) {
            float vv[10];
            #pragma unroll
            for (int o = 0; o < 10; ++o) vv[o] = v1s[t * 12 + o];
            #pragma unroll
            for (int p = 0; p < 5; ++p) {
                float s = ab2s[p];
                #pragma unroll
                for (int o = 0; o < 10; ++o) s += aw2s[p * 10 + o] * vv[o];
                float val = fmaxf(s, 0.f);
                v2row[t * 6 + p] = val;
                V2g[(size_t)(m0 + t) * 8 + p] = val;
            }
        }
        __syncthreads();
        if (t < 55) {
            const int a = MA[t], b = MB[t], c = MC[t];
            float s = 0.f;
            #pragma unroll 8
            for (int r = 0; r < 32; ++r) {
                float p = v2row[r * 6 + a];
                if (b >= 0) p *= v2row[r * 6 + b];
                if (c >= 0) p *= v2row[r * 6 + c];
                s += p;
            }
            mpart[bid * 56 + t] = s;
        }
    } else {
        #pragma unroll
        for (int i = 0; i < 4; ++i) {
            const int m = m0 + ty * 4 + i;
            float4 ov = make_float4(acc[i][0] + bias[tx * 4 + 0],
                                    acc[i][1] + bias[tx * 4 + 1],
                                    acc[i][2] + bias[tx * 4 + 2],
                                    acc[i][3] + bias[tx * 4 + 3]);
            *(float4*)(DTH + (size_t)m * CNN + tx * 4) = ov;
        }
    }
}

// ---- merged 3 iterations: fence-free atomic moment exchange ---------------
// 512 blocks x 256 thr x 16 rows. DTH + V2 rows live in LDS across all iters.
__global__ __launch_bounds__(256) void iter3_k(
    const float* __restrict__ DTH, const float* __restrict__ V2g,
    const float* __restrict__ mpart0,
    float* __restrict__ Matm, unsigned* __restrict__ ctr,
    const float* __restrict__ alpha_p,
    const float* __restrict__ wdtdT, const float* __restrict__ bdtd,
    const float* __restrict__ aw4, const float* __restrict__ ab4,
    const float* __restrict__ aw1, const float* __restrict__ ab1,
    const float* __restrict__ aw2, const float* __restrict__ ab2,
    const float* __restrict__ aw3, const float* __restrict__ ab3,
    float* __restrict__ outV)
{
    __shared__ float DTHs[16 * 128];
    __shared__ float A_lds[16 * 136];
    __shared__ float w4s[1280], aw1t[1280];
    __shared__ float b4s[128], bds[128];
    __shared__ float aw2s[52], ab1s[12], ab2s[8], w3s[52], b3s[12];
    __shared__ float v4s[16 * 12], v1s[16 * 12], v2row[16 * 6];
    __shared__ float S1s[8], M2f[25], T3f[125];
    __shared__ float redm[224];

    const int t  = threadIdx.x;
    const int m0 = blockIdx.x * 16;

    for (int i = t; i < 1280; i += 256) {
        w4s[i] = aw4[i];
        const int o = i >> 7, k = i & 127;
        aw1t[k * 10 + o] = aw1[i];
    }
    if (t < 128) { b4s[t] = ab4[t]; bds[t] = bdtd[t]; }
    if (t < 50)  { aw2s[t] = aw2[t]; w3s[t] = aw3[t]; }
    if (t < 10)  { ab1s[t] = ab1[t]; b3s[t] = ab3[t]; }
    if (t < 5)   ab2s[t] = ab2[t];
    #pragma unroll
    for (int i = 0; i < 8; ++i) {
        const int idx = t + i * 256;
        const int m = idx >> 7, k = idx & 127;
        DTHs[m * 128 + k] = DTH[(size_t)(m0 + m) * CNN + k];
    }
    if (t < 16) {
        #pragma unroll
        for (int c = 0; c < 5; ++c)
            v2row[t * 6 + c] = V2g[(size_t)(m0 + t) * 8 + c];
    }
    __syncthreads();

    const float alpha = alpha_p[0];

    for (int it = 0; it < 3; ++it) {
        // ---- moments for this iteration ----
        if (it == 0) {
            if (t < 224) {
                const int c = t % 56, grp = t / 56;
                const float* p = mpart0 + (size_t)grp * 64 * 56 + c;
                float s = 0.f;
                #pragma unroll 8
                for (int j = 0; j < 64; ++j) s += p[j * 56];
                redm[t] = s;
            }
            __syncthreads();
            if (t < 55) {
                float v = redm[t] + redm[56 + t] + redm[112 + t] + redm[168 + t];
                const int a = MA[t], b = MB[t], c = MC[t];
                if (t < 5)       S1s[t] = v;
                else if (t < 20) { M2f[a * 5 + b] = v; M2f[b * 5 + a] = v; }
                else {
                    T3f[(a * 5 + b) * 5 + c] = v; T3f[(a * 5 + c) * 5 + b] = v;
                    T3f[(b * 5 + a) * 5 + c] = v; T3f[(b * 5 + c) * 5 + a] = v;
                    T3f[(c * 5 + a) * 5 + b] = v; T3f[(c * 5 + b) * 5 + a] = v;
                }
            }
        } else {
            __syncthreads();
            if (t == 0) {
                const unsigned tgt = (unsigned)it * 512u;
                while (__hip_atomic_load(ctr, __ATOMIC_RELAXED,
                                         __HIP_MEMORY_SCOPE_AGENT) < tgt)
                    __builtin_amdgcn_s_sleep(8);
            }
            __syncthreads();
            if (t < 55) {
                float v = __hip_atomic_load(&Matm[(it - 1) * 56 + t],
                                            __ATOMIC_RELAXED, __HIP_MEMORY_SCOPE_AGENT);
                const int a = MA[t], b = MB[t], c = MC[t];
                if (t < 5)       S1s[t] = v;
                else if (t < 20) { M2f[a * 5 + b] = v; M2f[b * 5 + a] = v; }
                else {
                    T3f[(a * 5 + b) * 5 + c] = v; T3f[(a * 5 + c) * 5 + b] = v;
                    T3f[(b * 5 + a) * 5 + c] = v; T3f[(b * 5 + c) * 5 + a] = v;
                    T3f[(c * 5 + a) * 5 + b] = v; T3f[(c * 5 + b) * 5 + a] = v;
                }
            }
        }
        __syncthreads();

        // ---- per-row Taylor-softmax + L3 -> v4s (q from LDS v2row) ----
        if (t < 16) {
            float q[5];
            #pragma unroll
            for (int c = 0; c < 5; ++c) q[c] = v2row[t * 6 + c];
            float denom = (float)NR;
            float num[5];
            #pragma unroll
            for (int c = 0; c < 5; ++c) num[c] = S1s[c];
            #pragma unroll
            for (int a = 0; a < 5; ++a) {
                denom += q[a] * S1s[a];
                #pragma unroll
                for (int c = 0; c < 5; ++c) num[c] += q[a] * M2f[a * 5 + c];
            }
            #pragma unroll
            for (int a = 0; a < 5; ++a) {
                #pragma unroll
                for (int b = 0; b < 5; ++b) {
                    const float w = 0.5f * q[a] * q[b];
                    denom += w * M2f[a * 5 + b];
                    #pragma unroll
                    for (int c = 0; c < 5; ++c) num[c] += w * T3f[(a * 5 + b) * 5 + c];
                }
            }
            const float inv = 1.f / denom;
            float av[5];
            #pragma unroll
            for (int c = 0; c < 5; ++c) av[c] = num[c] * inv;
            #pragma unroll
            for (int o = 0; o < 10; ++o) {
                float s = b3s[o];
                #pragma unroll
                for (int c = 0; c < 5; ++c) s += w3s[o * 5 + c] * av[c];
                v4s[t * 12 + o] = fmaxf(s, 0.f);
            }
        }
        __syncthreads();

        // ---- build A[16][128] in LDS: DTHs + alpha*relu(L4 head) ----
        #pragma unroll
        for (int i = 0; i < 8; ++i) {
            const int idx = t + i * 256;
            const int m = idx >> 7, k = idx & 127;
            float pre = b4s[k];
            #pragma unroll
            for (int o = 0; o < 10; ++o) pre += w4s[k * 10 + o] * v4s[m * 12 + o];
            A_lds[m * 136 + k] = DTHs[m * 128 + k] + alpha * fmaxf(pre, 0.f);
        }
        __syncthreads();

        // ---- barrier-free GEMM: thread owns col n, 8 rows ----
        const int n = t & 127, rg = t >> 7;
        float acc[8] = {};
        #pragma unroll 4
        for (int k4 = 0; k4 < 32; ++k4) {
            const int k = k4 * 4;
            const float w0  = wdtdT[(size_t)(k + 0) * 128 + n];
            const float w1v = wdtdT[(size_t)(k + 1) * 128 + n];
            const float w2v = wdtdT[(size_t)(k + 2) * 128 + n];
            const float w3v = wdtdT[(size_t)(k + 3) * 128 + n];
            #pragma unroll
            for (int i = 0; i < 8; ++i) {
                const int m = rg * 8 + i;
                float4 av = *(const float4*)&A_lds[m * 136 + k];
                acc[i] += av.x * w0 + av.y * w1v + av.z * w2v + av.w * w3v;
            }
        }
        __syncthreads();

        if (it < 2) {
            #pragma unroll
            for (int i = 0; i < 8; ++i) {
                const int m = rg * 8 + i;
                A_lds[m * 136 + n] = fmaxf(acc[i] + bds[n], 0.f);   // Ct
            }
            __syncthreads();
            if (t < 160) {
                const int r = t / 10, o = t % 10;
                float s = ab1s[o];
                #pragma unroll 8
                for (int k = 0; k < 128; ++k) s += A_lds[r * 136 + k] * aw1t[k * 10 + o];
                v1s[r * 12 + o] = fmaxf(s, 0.f);
            }
            __syncthreads();
            if (t < 16) {
                float vv[10];
                #pragma unroll
                for (int o = 0; o < 10; ++o) vv[o] = v1s[t * 12 + o];
                #pragma unroll
                for (int p = 0; p < 5; ++p) {
                    float s = ab2s[p];
                    #pragma unroll
                    for (int o = 0; o < 10; ++o) s += aw2s[p * 10 + o] * vv[o];
                    v2row[t * 6 + p] = fmaxf(s, 0.f);
                }
            }
            __syncthreads();
            if (t < 55) {
                const int a = MA[t], b = MB[t], c = MC[t];
                float s = 0.f;
                #pragma unroll
                for (int r = 0; r < 16; ++r) {
                    float p = v2row[r * 6 + a];
                    if (b >= 0) p *= v2row[r * 6 + b];
                    if (c >= 0) p *= v2row[r * 6 + c];
                    s += p;
                }
                __hip_atomic_fetch_add(&Matm[it * 56 + t], s,
                                       __ATOMIC_RELAXED, __HIP_MEMORY_SCOPE_AGENT);
                asm volatile("s_waitcnt vmcnt(0)" ::: "memory");
            }
            __syncthreads();
            if (t == 0)
                __hip_atomic_fetch_add(ctr, 1u, __ATOMIC_RELAXED,
                                       __HIP_MEMORY_SCOPE_AGENT);
        } else {
            #pragma unroll
            for (int i = 0; i < 8; ++i) {
                const int m = rg * 8 + i;
                outV[(size_t)(m0 + m) * CNN + n] = fmaxf(acc[i] + bds[n], 0.f);
            }
        }
    }
}

// ------------------------------------------------------ H_R = V @ wdt (f32)
__global__ __launch_bounds__(256) void gemm_hr_k(
    const float* __restrict__ Vf, const float* __restrict__ wdt,
    float* __restrict__ out)
{
    __shared__ float As[8][68];
    __shared__ float Bs[8][68];
    const int t  = threadIdx.x;
    const int m0 = blockIdx.x * 64;
    const int n0 = blockIdx.y * 64;
    const int tx = t & 15, ty = t >> 4;
    const int lm = t >> 2;
    const int lk = (t & 3) * 2;
    const int bkk = t >> 5;
    const int bnn = (t & 31) * 2;
    float acc[4][4] = {};
    for (int k0 = 0; k0 < CNN; k0 += 8) {
        float2 a2 = *(const float2*)(Vf + (size_t)(m0 + lm) * CNN + k0 + lk);
        float2 w2 = make_float2(0.f, 0.f);
        if (n0 + bnn < CIN)
            w2 = *(const float2*)(wdt + (size_t)(k0 + bkk) * CIN + n0 + bnn);
        __syncthreads();
        As[lk][lm]     = a2.x;
        As[lk + 1][lm] = a2.y;
        Bs[bkk][bnn]     = w2.x;
        Bs[bkk][bnn + 1] = w2.y;
        __syncthreads();
        #pragma unroll
        for (int kk = 0; kk < 8; ++kk) {
            float a[4], b[4];
            #pragma unroll
            for (int i = 0; i < 4; ++i) a[i] = As[kk][ty * 4 + i];
            #pragma unroll
            for (int j = 0; j < 4; ++j) b[j] = Bs[kk][tx * 4 + j];
            #pragma unroll
            for (int i = 0; i < 4; ++i)
                #pragma unroll
                for (int j = 0; j < 4; ++j)
                    acc[i][j] += a[i] * b[j];
        }
    }
    #pragma unroll
    for (int i = 0; i < 4; ++i) {
        const int m = m0 + ty * 4 + i;
        #pragma unroll
        for (int j = 0; j < 4; ++j) {
            const int n = n0 + tx * 4 + j;
            if (n < CIN) out[(size_t)m * CIN + n] = acc[i][j];
        }
    }
}

// --------------------------------------------------------------- launcher
extern "C" void kernel_launch(void* const* d_in, const int* in_sizes, int n_in,
                              void* d_out, int out_size, void* d_ws, size_t ws_size,
                              hipStream_t stream)
{
    (void)in_sizes; (void)n_in; (void)out_size; (void)ws_size;
    const float* H     = (const float*)d_in[0];
    const float* alpha = (const float*)d_in[1];
    const float* gamma = (const float*)d_in[2];
    const float* beta  = (const float*)d_in[3];
    const float* w1    = (const float*)d_in[4];
    const float* b1    = (const float*)d_in[5];
    const float* wdt   = (const float*)d_in[6];
    const float* bdt   = (const float*)d_in[7];
    const float* wdtd  = (const float*)d_in[8];
    const float* bdtd  = (const float*)d_in[9];
    const float* aw1   = (const float*)d_in[10];
    const float* ab1   = (const float*)d_in[11];
    const float* aw2   = (const float*)d_in[12];
    const float* ab2   = (const float*)d_in[13];
    const float* aw3   = (const float*)d_in[14];
    const float* ab3   = (const float*)d_in[15];
    const float* aw4   = (const float*)d_in[16];
    const float* ab4   = (const float*)d_in[17];

    float* ws    = (float*)d_ws;
    float* DTH   = ws + OFF_DTH;
    float* V2g   = ws + OFF_V2;
    float* mp    = ws + OFF_MP;
    float* wdtdT = ws + OFF_WT;
    float* Matm  = ws + OFF_ATM;
    unsigned* ctr = (unsigned*)(ws + OFF_ATM + 112);

    float* outV  = (float*)d_out;
    float* outHR = outV + (size_t)NR * CNN;

    bn1_k<<<80, 256, 0, stream>>>(H, wdtd, ws);
    gemm_bn_k<<<512, 256, 0, stream>>>(H, w1, b1, wdt, bdt, aw1, ab1, aw2, ab2,
                                       gamma, beta, ws, DTH, V2g, mp);
    iter3_k<<<512, 256, 0, stream>>>(DTH, V2g, mp, Matm, ctr, alpha, wdtdT, bdtd,
                                     aw4, ab4, aw1, ab1, aw2, ab2, aw3, ab3, outV);
    gemm_hr_k<<<dim3(128, 4), 256, 0, stream>>>(outV, wdt, outHR);
}

// Round 18
// 104.655 us; speedup vs baseline: 1.3613x; 1.3613x over previous
//
#include <hip/hip_runtime.h>

#define NR   8192
#define CIN  200
#define CNN  128
#define BN_EPS 1e-5f

// ws float offsets
#define OFF_BNPART 0                           // 64 blocks * 400
#define OFF_DTH    (OFF_BNPART + 64 * 400)
#define OFF_V2     (OFF_DTH + NR * CNN)        // [NR][8] f32 (cols 0..4 used)
#define OFF_MPA    (OFF_V2 + NR * 8)           // 56 x 256 moment partials (transposed)
#define OFF_MPB    (OFF_MPA + 56 * 256)

// moment component tables: t<5 -> S1[A]; 5<=t<20 -> M2[A][B]; 20<=t<55 -> T3[A][B][C]
__device__ const int MA[55] = {0,1,2,3,4,
    0,0,0,0,0,1,1,1,1,2,2,2,3,3,4,
    0,0,0,0,0,0,0,0,0,0,0,0,0,0,0,
    1,1,1,1,1,1,1,1,1,1,
    2,2,2,2,2,2,
    3,3,3,
    4};
__device__ const int MB[55] = {-1,-1,-1,-1,-1,
    0,1,2,3,4,1,2,3,4,2,3,4,3,4,4,
    0,0,0,0,0,1,1,1,1,2,2,2,3,3,4,
    1,1,1,1,2,2,2,3,3,4,
    2,2,2,3,3,4,
    3,3,4,
    4};
__device__ const int MC[55] = {-1,-1,-1,-1,-1,
    -1,-1,-1,-1,-1,-1,-1,-1,-1,-1,-1,-1,-1,-1,-1,
    0,1,2,3,4,1,2,3,4,2,3,4,3,4,4,
    1,2,3,4,2,3,4,3,4,4,
    2,3,4,3,4,4,
    3,4,4,
    4};

// ---------------- BN pass 1: row-block partial sums ------------------------
__global__ __launch_bounds__(256) void bn1_k(
    const float* __restrict__ H, float* __restrict__ ws)
{
    const int t = threadIdx.x;
    if (t >= CIN) return;
    const float* p = H + (size_t)blockIdx.x * 128 * CIN + t;
    float s = 0.f, q = 0.f;
    #pragma unroll 8
    for (int r = 0; r < 128; ++r) { float v = p[(size_t)r * CIN]; s += v; q += v * v; }
    ws[OFF_BNPART + blockIdx.x * 400 + t]       = s;
    ws[OFF_BNPART + blockIdx.x * 400 + 200 + t] = q;
}

// ---------------- BN finalize + dual GEMM + l12 epilogue + moment partials -
__global__ __launch_bounds__(256) void gemm_bn_k(
    const float* __restrict__ H, const float* __restrict__ w1,
    const float* __restrict__ b1, const float* __restrict__ wdt,
    const float* __restrict__ bdt,
    const float* __restrict__ aw1, const float* __restrict__ ab1,
    const float* __restrict__ aw2, const float* __restrict__ ab2,
    const float* __restrict__ gamma, const float* __restrict__ beta,
    float* __restrict__ ws, float* __restrict__ DTH,
    float* __restrict__ V2g, float* __restrict__ mpart)
{
    __shared__ float smem[8192];
    float* scs  = smem;          // 256
    float* shs  = smem + 256;    // 256
    float* bias = smem + 512;    // 128
    float* aw1s = smem + 768;    // 1280
    float* aw2s = smem + 2048;   // 64
    float* ab1s = smem + 2112;   // 16
    float* ab2s = smem + 2128;   // 16
    float* As   = smem + 2144;   // [8][36]
    float* Bs   = smem + 2432;   // [8][136]
    float* Ct   = smem + 3520;   // [32][133]
    float* v1s  = smem + 7776;   // [32][12]
    float* v2row = smem + 2144;  // [32][6] (reuses As region post-GEMM)

    const int t   = threadIdx.x;
    const int bid = blockIdx.x;
    const bool isV = (bid < 256);
    const int  m0  = (bid & 255) * 32;
    const float* bnpart = ws + OFF_BNPART;

    if (t < CIN) {
        float s = 0.f, q = 0.f;
        const float* p = bnpart + t;
        #pragma unroll 8
        for (int b = 0; b < 64; ++b) { s += p[b * 400]; q += p[b * 400 + 200]; }
        float mu  = s * (1.f / NR);
        float var = q * (1.f / NR) - mu * mu;
        float rstd = rsqrtf(var + BN_EPS);
        float sc  = rstd * gamma[t];
        scs[t] = sc; shs[t] = beta[t] - mu * sc;
    }
    if (t < CNN) bias[t] = isV ? b1[t] : bdt[t];
    if (isV) {
        for (int i = t; i < 1280; i += 256) aw1s[i] = aw1[i];
        if (t < 50) aw2s[t] = aw2[t];
        if (t < 10) ab1s[t] = ab1[t];
        if (t < 5)  ab2s[t] = ab2[t];
    }
    const int am = t >> 3, ak = t & 7;
    const int bn_ = t >> 1, bk4 = (t & 1) * 4;
    const float* brow = (isV ? w1 : wdt) + (size_t)bn_ * CIN + bk4;
    const float* arow = H + (size_t)(m0 + am) * CIN + ak;
    const int tx = t & 31, ty = t >> 5;
    float acc[4][4] = {};
    __syncthreads();

    for (int k0 = 0; k0 < CIN; k0 += 8) {
        const int k = k0 + ak;
        float  aval = arow[k0] * scs[k] + shs[k];
        float4 bv   = *(const float4*)(brow + k0);
        __syncthreads();
        As[ak * 36 + am] = aval;
        Bs[(bk4 + 0) * 136 + bn_] = bv.x; Bs[(bk4 + 1) * 136 + bn_] = bv.y;
        Bs[(bk4 + 2) * 136 + bn_] = bv.z; Bs[(bk4 + 3) * 136 + bn_] = bv.w;
        __syncthreads();
        #pragma unroll
        for (int kk = 0; kk < 8; ++kk) {
            float4 av  = *(const float4*)&As[kk * 36 + ty * 4];
            float4 bv4 = *(const float4*)&Bs[kk * 136 + tx * 4];
            float a[4] = {av.x, av.y, av.z, av.w};
            float b[4] = {bv4.x, bv4.y, bv4.z, bv4.w};
            #pragma unroll
            for (int i = 0; i < 4; ++i)
                #pragma unroll
                for (int j = 0; j < 4; ++j)
                    acc[i][j] += a[i] * b[j];
        }
    }

    if (isV) {
        #pragma unroll
        for (int i = 0; i < 4; ++i) {
            const int m = ty * 4 + i;
            #pragma unroll
            for (int j = 0; j < 4; ++j) {
                const int n = tx * 4 + j;
                Ct[m * 133 + n] = fmaxf(acc[i][j] + bias[n], 0.f);
            }
        }
        __syncthreads();
        for (int o = ty; o < 10; o += 8) {
            const int row = tx;
            float s = ab1s[o];
            const float* wr = &aw1s[o * 128];
            #pragma unroll 8
            for (int k = 0; k < 128; ++k) s += Ct[row * 133 + k] * wr[k];
            v1s[row * 12 + o] = fmaxf(s, 0.f);
        }
        __syncthreads();
        if (t < 32) {
            float vv[10];
            #pragma unroll
            for (int o = 0; o < 10; ++o) vv[o] = v1s[t * 12 + o];
            #pragma unroll
            for (int p = 0; p < 5; ++p) {
                float s = ab2s[p];
                #pragma unroll
                for (int o = 0; o < 10; ++o) s += aw2s[p * 10 + o] * vv[o];
                float val = fmaxf(s, 0.f);
                v2row[t * 6 + p] = val;
                V2g[(size_t)(m0 + t) * 8 + p] = val;
            }
        }
        __syncthreads();
        if (t < 55) {
            const int a = MA[t], b = MB[t], c = MC[t];
            float s = 0.f;
            #pragma unroll 8
            for (int r = 0; r < 32; ++r) {
                float p = v2row[r * 6 + a];
                if (b >= 0) p *= v2row[r * 6 + b];
                if (c >= 0) p *= v2row[r * 6 + c];
                s += p;
            }
            mpart[(size_t)t * 256 + bid] = s;      // transposed [comp][block]
        }
    } else {
        #pragma unroll
        for (int i = 0; i < 4; ++i) {
            const int m = m0 + ty * 4 + i;
            float4 ov = make_float4(acc[i][0] + bias[tx * 4 + 0],
                                    acc[i][1] + bias[tx * 4 + 1],
                                    acc[i][2] + bias[tx * 4 + 2],
                                    acc[i][3] + bias[tx * 4 + 3]);
            *(float4*)(DTH + (size_t)m * CNN + tx * 4) = ov;
        }
    }
}

// ---------------- iteration: moment-form attention + L3 + L4 + GEMM --------
// 256 blocks x 32 rows. av = (S1 + q·M2 + ½qq:T3)/(N + q·S1 + ½q·M2·q).
__global__ __launch_bounds__(256) void iter_k(
    const float* __restrict__ DTH, const float* __restrict__ V2g_in,
    const float* __restrict__ mpartIn,
    const float* __restrict__ alpha_p,
    const float* __restrict__ wdtd, const float* __restrict__ bdtd,
    const float* __restrict__ aw4, const float* __restrict__ ab4,
    const float* __restrict__ aw1, const float* __restrict__ ab1,
    const float* __restrict__ aw2, const float* __restrict__ ab2,
    const float* __restrict__ aw3, const float* __restrict__ ab3,
    float* __restrict__ V2g_out, float* __restrict__ mpartOut,
    float* __restrict__ outV)
{
    __shared__ float As[8 * 36];
    __shared__ float Bs[8 * 136];
    __shared__ float w4s[1280];
    __shared__ float aw1t[1280];        // transposed [k*10+o]
    __shared__ float b4s[128], bds[128];
    __shared__ float aw2s[52], ab1s[12], ab2s[8];
    __shared__ float w3s[52], b3s[12];
    __shared__ float Ct[32 * 133];
    __shared__ float v1s[32 * 12];
    __shared__ float v4s[32 * 12];
    __shared__ float v2row[32 * 6];
    __shared__ float S1s[8], M2f[25], T3f[125];
    __shared__ float redm[224];

    const int t  = threadIdx.x;
    const int m0 = blockIdx.x * 32;
    const bool last = (outV != nullptr);

    for (int i = t; i < 1280; i += 256) {
        w4s[i] = aw4[i];
        const int o = i >> 7, k = i & 127;
        aw1t[k * 10 + o] = aw1[i];
    }
    if (t < 128) { b4s[t] = ab4[t]; bds[t] = bdtd[t]; }
    if (t < 50)  { aw2s[t] = aw2[t]; w3s[t] = aw3[t]; }
    if (t < 10)  { ab1s[t] = ab1[t]; b3s[t] = ab3[t]; }
    if (t < 5)   ab2s[t] = ab2[t];

    // ---- reduce 256 moment partials -> 55 moments (coalesced, transposed) -
    {
        const int comp = t % 56, grp = t / 56;
        if (t < 224) {
            const float* p = mpartIn + (size_t)comp * 256 + grp * 64;
            float rsum = 0.f;
            #pragma unroll 8
            for (int j = 0; j < 64; ++j) rsum += p[j];
            redm[t] = rsum;
        }
    }
    __syncthreads();
    if (t < 55) {
        float v = redm[t] + redm[56 + t] + redm[112 + t] + redm[168 + t];
        const int a = MA[t], b = MB[t], c = MC[t];
        if (t < 5)       S1s[t] = v;
        else if (t < 20) { M2f[a * 5 + b] = v; M2f[b * 5 + a] = v; }
        else {
            T3f[(a * 5 + b) * 5 + c] = v; T3f[(a * 5 + c) * 5 + b] = v;
            T3f[(b * 5 + a) * 5 + c] = v; T3f[(b * 5 + c) * 5 + a] = v;
            T3f[(c * 5 + a) * 5 + b] = v; T3f[(c * 5 + b) * 5 + a] = v;
        }
    }
    __syncthreads();

    // ---- per-row Taylor-softmax eval + L3 -> v4s ----
    if (t < 32) {
        float q[5];
        #pragma unroll
        for (int c = 0; c < 5; ++c) q[c] = V2g_in[(size_t)(m0 + t) * 8 + c];
        float denom = (float)NR;
        float num[5];
        #pragma unroll
        for (int c = 0; c < 5; ++c) num[c] = S1s[c];
        #pragma unroll
        for (int a = 0; a < 5; ++a) {
            denom += q[a] * S1s[a];
            #pragma unroll
            for (int c = 0; c < 5; ++c) num[c] += q[a] * M2f[a * 5 + c];
        }
        #pragma unroll
        for (int a = 0; a < 5; ++a) {
            #pragma unroll
            for (int b = 0; b < 5; ++b) {
                const float w = 0.5f * q[a] * q[b];
                denom += w * M2f[a * 5 + b];
                #pragma unroll
                for (int c = 0; c < 5; ++c) num[c] += w * T3f[(a * 5 + b) * 5 + c];
            }
        }
        const float inv = 1.f / denom;
        float av[5];
        #pragma unroll
        for (int c = 0; c < 5; ++c) av[c] = num[c] * inv;
        #pragma unroll
        for (int o = 0; o < 10; ++o) {
            float s = b3s[o];
            #pragma unroll
            for (int c = 0; c < 5; ++c) s += w3s[o * 5 + c] * av[c];
            v4s[t * 12 + o] = fmaxf(s, 0.f);
        }
    }
    __syncthreads();

    // ---- GEMM: A[32x128] (DTH + alpha*relu(L4(v4))) @ wdtd^T ----
    const float alpha = alpha_p[0];
    const int am = t >> 3, ak = t & 7;
    float v4r[10];
    #pragma unroll
    for (int o = 0; o < 10; ++o) v4r[o] = v4s[am * 12 + o];
    const int bn_ = t >> 1, bk4 = (t & 1) * 4;
    const float* brow = wdtd + (size_t)bn_ * CNN + bk4;
    const float* arow = DTH + (size_t)(m0 + am) * CNN + ak;
    const int tx = t & 31, ty = t >> 5;
    float acc[4][4] = {};
    __syncthreads();

    for (int k0 = 0; k0 < CNN; k0 += 8) {
        const int k = k0 + ak;
        float pre = b4s[k];
        #pragma unroll
        for (int o = 0; o < 10; ++o) pre += w4s[k * 10 + o] * v4r[o];
        float  aval = arow[k0] + alpha * fmaxf(pre, 0.f);
        float4 bv   = *(const float4*)(brow + k0);
        __syncthreads();
        As[ak * 36 + am] = aval;
        Bs[(bk4 + 0) * 136 + bn_] = bv.x; Bs[(bk4 + 1) * 136 + bn_] = bv.y;
        Bs[(bk4 + 2) * 136 + bn_] = bv.z; Bs[(bk4 + 3) * 136 + bn_] = bv.w;
        __syncthreads();
        #pragma unroll
        for (int kk = 0; kk < 8; ++kk) {
            float4 av  = *(const float4*)&As[kk * 36 + ty * 4];
            float4 bv4 = *(const float4*)&Bs[kk * 136 + tx * 4];
            float a[4] = {av.x, av.y, av.z, av.w};
            float b[4] = {bv4.x, bv4.y, bv4.z, bv4.w};
            #pragma unroll
            for (int i = 0; i < 4; ++i)
                #pragma unroll
                for (int j = 0; j < 4; ++j)
                    acc[i][j] += a[i] * b[j];
        }
    }

    if (!last) {
        #pragma unroll
        for (int i = 0; i < 4; ++i) {
            const int m = ty * 4 + i;
            #pragma unroll
            for (int j = 0; j < 4; ++j) {
                const int n = tx * 4 + j;
                Ct[m * 133 + n] = fmaxf(acc[i][j] + bds[n], 0.f);
            }
        }
        __syncthreads();
        for (int o = ty; o < 10; o += 8) {
            const int row = tx;
            float s = ab1s[o];
            #pragma unroll 8
            for (int k = 0; k < 128; ++k) s += Ct[row * 133 + k] * aw1t[k * 10 + o];
            v1s[row * 12 + o] = fmaxf(s, 0.f);
        }
        __syncthreads();
        if (t < 32) {
            float vv[10];
            #pragma unroll
            for (int o = 0; o < 10; ++o) vv[o] = v1s[t * 12 + o];
            #pragma unroll
            for (int p = 0; p < 5; ++p) {
                float s = ab2s[p];
                #pragma unroll
                for (int o = 0; o < 10; ++o) s += aw2s[p * 10 + o] * vv[o];
                float val = fmaxf(s, 0.f);
                v2row[t * 6 + p] = val;
                V2g_out[(size_t)(m0 + t) * 8 + p] = val;
            }
        }
        __syncthreads();
        if (t < 55) {
            const int a = MA[t], b = MB[t], c = MC[t];
            float s = 0.f;
            #pragma unroll 8
            for (int r = 0; r < 32; ++r) {
                float p = v2row[r * 6 + a];
                if (b >= 0) p *= v2row[r * 6 + b];
                if (c >= 0) p *= v2row[r * 6 + c];
                s += p;
            }
            mpartOut[(size_t)t * 256 + blockIdx.x] = s;   // transposed
        }
    } else {
        #pragma unroll
        for (int i = 0; i < 4; ++i) {
            const int m = m0 + ty * 4 + i;
            float4 ov = make_float4(fmaxf(acc[i][0] + bds[tx * 4 + 0], 0.f),
                                    fmaxf(acc[i][1] + bds[tx * 4 + 1], 0.f),
                                    fmaxf(acc[i][2] + bds[tx * 4 + 2], 0.f),
                                    fmaxf(acc[i][3] + bds[tx * 4 + 3], 0.f));
            *(float4*)(outV + (size_t)m * CNN + tx * 4) = ov;
        }
    }
}

// ------------------------------------------------------ H_R = V @ wdt (f32)
__global__ __launch_bounds__(256) void gemm_hr_k(
    const float* __restrict__ Vf, const float* __restrict__ wdt,
    float* __restrict__ out)
{
    __shared__ float As[8][68];
    __shared__ float Bs[8][68];
    const int t  = threadIdx.x;
    const int m0 = blockIdx.x * 64;
    const int n0 = blockIdx.y * 64;
    const int tx = t & 15, ty = t >> 4;
    const int lm = t >> 2;
    const int lk = (t & 3) * 2;
    const int bkk = t >> 5;
    const int bnn = (t & 31) * 2;
    float acc[4][4] = {};
    for (int k0 = 0; k0 < CNN; k0 += 8) {
        float2 a2 = *(const float2*)(Vf + (size_t)(m0 + lm) * CNN + k0 + lk);
        float2 w2 = make_float2(0.f, 0.f);
        if (n0 + bnn < CIN)
            w2 = *(const float2*)(wdt + (size_t)(k0 + bkk) * CIN + n0 + bnn);
        __syncthreads();
        As[lk][lm]     = a2.x;
        As[lk + 1][lm] = a2.y;
        Bs[bkk][bnn]     = w2.x;
        Bs[bkk][bnn + 1] = w2.y;
        __syncthreads();
        #pragma unroll
        for (int kk = 0; kk < 8; ++kk) {
            float a[4], b[4];
            #pragma unroll
            for (int i = 0; i < 4; ++i) a[i] = As[kk][ty * 4 + i];
            #pragma unroll
            for (int j = 0; j < 4; ++j) b[j] = Bs[kk][tx * 4 + j];
            #pragma unroll
            for (int i = 0; i < 4; ++i)
                #pragma unroll
                for (int j = 0; j < 4; ++j)
                    acc[i][j] += a[i] * b[j];
        }
    }
    #pragma unroll
    for (int i = 0; i < 4; ++i) {
        const int m = m0 + ty * 4 + i;
        #pragma unroll
        for (int j = 0; j < 4; ++j) {
            const int n = n0 + tx * 4 + j;
            if (n < CIN) out[(size_t)m * CIN + n] = acc[i][j];
        }
    }
}

// --------------------------------------------------------------- launcher
extern "C" void kernel_launch(void* const* d_in, const int* in_sizes, int n_in,
                              void* d_out, int out_size, void* d_ws, size_t ws_size,
                              hipStream_t stream)
{
    (void)in_sizes; (void)n_in; (void)out_size; (void)ws_size;
    const float* H     = (const float*)d_in[0];
    const float* alpha = (const float*)d_in[1];
    const float* gamma = (const float*)d_in[2];
    const float* beta  = (const float*)d_in[3];
    const float* w1    = (const float*)d_in[4];
    const float* b1    = (const float*)d_in[5];
    const float* wdt   = (const float*)d_in[6];
    const float* bdt   = (const float*)d_in[7];
    const float* wdtd  = (const float*)d_in[8];
    const float* bdtd  = (const float*)d_in[9];
    const float* aw1   = (const float*)d_in[10];
    const float* ab1   = (const float*)d_in[11];
    const float* aw2   = (const float*)d_in[12];
    const float* ab2   = (const float*)d_in[13];
    const float* aw3   = (const float*)d_in[14];
    const float* ab3   = (const float*)d_in[15];
    const float* aw4   = (const float*)d_in[16];
    const float* ab4   = (const float*)d_in[17];

    float* ws    = (float*)d_ws;
    float* DTH   = ws + OFF_DTH;
    float* V2g   = ws + OFF_V2;
    float* mpA   = ws + OFF_MPA;
    float* mpB   = ws + OFF_MPB;

    float* outV  = (float*)d_out;
    float* outHR = outV + (size_t)NR * CNN;

    bn1_k<<<64, 256, 0, stream>>>(H, ws);
    gemm_bn_k<<<512, 256, 0, stream>>>(H, w1, b1, wdt, bdt, aw1, ab1, aw2, ab2,
                                       gamma, beta, ws, DTH, V2g, mpA);
    iter_k<<<256, 256, 0, stream>>>(DTH, V2g, mpA, alpha, wdtd, bdtd,
                                    aw4, ab4, aw1, ab1, aw2, ab2, aw3, ab3,
                                    V2g, mpB, nullptr);
    iter_k<<<256, 256, 0, stream>>>(DTH, V2g, mpB, alpha, wdtd, bdtd,
                                    aw4, ab4, aw1, ab1, aw2, ab2, aw3, ab3,
                                    V2g, mpA, nullptr);
    iter_k<<<256, 256, 0, stream>>>(DTH, V2g, mpA, alpha, wdtd, bdtd,
                                    aw4, ab4, aw1, ab1, aw2, ab2, aw3, ab3,
                                    nullptr, nullptr, outV);
    gemm_hr_k<<<dim3(128, 4), 256, 0, stream>>>(outV, wdt, outHR);
}